// Round 3
// baseline (533.928 us; speedup 1.0000x reference)
//
#include <hip/hip_runtime.h>
#include <hip/hip_bf16.h>

// Problem: B=16,S=64 -> BS=1024 sequences, L=128 tokens, D=512, F=256 filters
// per conv width Kw in {3,4,5}, V=30000.
// out[bs, c*256 + f] = relu(max_t (conv_c(x)[t,f]) + b_c[f]), fp32.
//
// R5: fragment-ordered wq, barrier-free K loop: 514 us (conv 405, Mfma 47%).
// R6: fused gather + 16 waves FAILED (562): gather L2 storm + B starvation.
// R7: persistent c-merged blocks, 2 gathers/bs, depth-4 B ring: 442 us
//     (conv 363, Mfma 58%). Conflicts = 4 cyc per ds_read_b128, layout-
//     invariant -> LDS effective ~85 B/cyc is the binding pipe at 16x16.
// R8: (a) 32x32x16 MFMA: 2x FLOP per operand byte (A-LDS 16 KB per 258-cyc
//     round vs 64 KB per 621 at 16x16) and floor 199->165 us (2495 TF rate);
//     wave grid 4m x 4n, wave tile 32x64, acc = 2 x f32x16.
//     (b) flat B ring across phases/convs/bs: tail prefetch slots load the
//     next stream's k16 0..3 (were dead clamps) -> zero serial B prologs
//     after the block prolog. pack_w re-ordered to 32x32 fragments.

typedef __bf16 bf16x8 __attribute__((ext_vector_type(8)));
typedef float f32x4 __attribute__((ext_vector_type(4)));
typedef float f32x16 __attribute__((ext_vector_type(16)));

#define ROWS 132                      // 128 real + 4 zero rows (K=5 window)
#define ROWB 512                      // bytes per row per half-D buffer
#define BUF_BYTES (ROWS * ROWB)       // 67584
#define RED_OFF (2 * BUF_BYTES)       // 135168
#define LDS_TOTAL (RED_OFF + 4096)    // 139264 (red: 4 x 256 f32)
#define WQ_ELEMS 1572864              // 3072 chunks * 512 elem

// -------- pack_w: 32x32-fragment-ordered chunks -----------------------------
// Chunk g = (c, k16, n32), 1024 B = 64 lanes x 16 B. Element (lane, j):
//   f = n32*32 + (lane&31), tap = k16>>5, d = (k16&31)*16 + (lane>>5)*8 + j
//   src = w_c[f][d][tap]  (layout [F][D][Kw]).  Chunk order: [c][k16][n32].
// Chunk bases (chunks): c0 = 0 (768), c1 = 768 (1024), c2 = 1792 (1280).
__global__ void pack_w_kernel(const float* __restrict__ w3,
                              const float* __restrict__ w4,
                              const float* __restrict__ w5,
                              __bf16* __restrict__ wq) {
    const int t    = blockIdx.x * 256 + threadIdx.x;  // 0..196607
    const int g    = t >> 6;                          // chunk 0..3071
    const int lane = t & 63;
    int rel, Kw; const float* w;
    if (g < 768)       { rel = g;        Kw = 3; w = w3; }
    else if (g < 1792) { rel = g - 768;  Kw = 4; w = w4; }
    else               { rel = g - 1792; Kw = 5; w = w5; }
    const int k16 = rel >> 3;                         // 0..Kw*32-1
    const int n32 = rel & 7;
    const int f   = n32 * 32 + (lane & 31);
    const int tap = k16 >> 5;
    const int d0  = (k16 & 31) * 16 + (lane >> 5) * 8;
    const float* src = w + ((size_t)f * 512 + d0) * Kw + tap;
    bf16x8 o;
#pragma unroll
    for (int j = 0; j < 8; ++j) o[j] = (__bf16)src[j * Kw];
    *(bf16x8*)(wq + (size_t)t * 8) = o;
}

// ---------------- persistent fused gather + conv GEMM -----------------------
// Grid 256 (1 block/CU), 4 bs/block, 1024 thr = 16 waves as 4m x 4n.
// Wave tile 32x64 = 1x2 of 32x32x16 bf16. A: two half-D slabs (h0/h1),
// XOR-swizzled, resident across all 3 convs (2 gathers/bs). B: 32x32
// fragment chunks, flat depth-4 register ring spanning phase/conv/bs
// boundaries. Barrier-free K loop (barriers only at restage/epilogue).
__global__ __launch_bounds__(1024, 4) void conv_gemm_kernel(
        const int* __restrict__ text,
        const float* __restrict__ embed,
        const __bf16* __restrict__ wq,
        const float* __restrict__ b3,
        const float* __restrict__ b4,
        const float* __restrict__ b5,
        float* __restrict__ out) {
    extern __shared__ char lds[];
    float* const red = (float*)(lds + RED_OFF);

    const int tid  = threadIdx.x;
    const int lane = tid & 63;
    const int wave = tid >> 6;         // 0..15
    const int wm   = wave & 3;         // m-slice (32 rows)
    const int wn   = wave >> 2;        // n-slice (64 cols)
    const int l31  = lane & 31;
    const int lh   = lane >> 5;
    const int sr   = tid >> 5;         // staging row-in-pass 0..31
    const int sc   = tid & 31;         // staging col 0..31 (x16B)

    const int bsbase = blockIdx.x * 4;

    // ---- gather staging: 2 passes (64 rows) per pair, 16 B dst/thread ----
    float4 G[4];
    auto issuePair = [&](int nbs, int h, int p0) {
#pragma unroll
        for (int p = 0; p < 2; ++p) {
            const int r = (p0 + p) * 32 + sr;
            const int tok = text[nbs * 128 + r];
            const float* src = embed + (size_t)tok * 512 + h * 256 + sc * 8;
            G[p * 2]     = *(const float4*)(src);
            G[p * 2 + 1] = *(const float4*)(src + 4);
        }
    };
    auto writePair = [&](char* bufp, int p0) {
#pragma unroll
        for (int p = 0; p < 2; ++p) {
            const int r = (p0 + p) * 32 + sr;
            const float4 v0 = G[p * 2], v1 = G[p * 2 + 1];
            bf16x8 o;
            o[0] = (__bf16)v0.x; o[1] = (__bf16)v0.y;
            o[2] = (__bf16)v0.z; o[3] = (__bf16)v0.w;
            o[4] = (__bf16)v1.x; o[5] = (__bf16)v1.y;
            o[6] = (__bf16)v1.z; o[7] = (__bf16)v1.w;
            *(bf16x8*)(bufp + r * ROWB + (((sc ^ (r & 7))) << 4)) = o;
        }
    };

    f32x16 acc[2];
    bf16x8 Br[4][2];
    const __bf16* const bpL = wq + (size_t)wn * 1024 + (size_t)lane * 8;

    // ---- block prolog: stage bs0 both halves, zero pad rows, fill ring ----
    issuePair(bsbase, 0, 0); writePair(lds, 0);
    issuePair(bsbase, 0, 2); writePair(lds, 2);
    issuePair(bsbase, 1, 0); writePair(lds + BUF_BYTES, 0);
    issuePair(bsbase, 1, 2); writePair(lds + BUF_BYTES, 2);
    if (tid < 128) {                   // rows 128..131, both buffers, once
        const int r = 128 + sr;
        const int off = r * ROWB + ((sc ^ (r & 7)) << 4);
        bf16x8 z = {};
        *(bf16x8*)(lds + off) = z;
        *(bf16x8*)(lds + BUF_BYTES + off) = z;
    }
#pragma unroll
    for (int k = 0; k < 4; ++k) {      // ring: c0 k16 0..3
        Br[k][0] = *(const bf16x8*)(bpL + k * 4096);
        Br[k][1] = *(const bf16x8*)(bpL + k * 4096 + 512);
    }
    __syncthreads();

#pragma unroll 1
    for (int i = 0; i < 4; ++i) {
        const int bs  = bsbase + i;
        const int nbs = bs + 1;
        const bool stg = (i < 3);
#pragma unroll 1
        for (int c = 0; c < 3; ++c) {
            const int KW = 3 + c;
            const size_t cb  = (c == 0) ? 0 : (c == 1) ? 393216 : 917504;
            const size_t cbn = (c == 2) ? 0 : (c == 0) ? 393216 : 917504;
            const __bf16* bpc = bpL + cb;
            const __bf16* bpn = bpL + cbn;
            const bool lastc = stg && (c == 2);
#pragma unroll
            for (int r = 0; r < 16; ++r) { acc[0][r] = 0.f; acc[1][r] = 0.f; }

            if (lastc) issuePair(nbs, 0, 0);   // h0 rows 0..63: hide under h0

            const int arow = wm * 32 + l31;
            // cold A: h0 tap0 s0
            bf16x8 a_cur = *(const bf16x8*)(
                lds + arow * 512 + ((lh ^ (arow & 7)) << 4));

#pragma unroll 1
            for (int h = 0; h < 2; ++h) {
                const int hb = h * 16;
                const int bo = h ? BUF_BYTES : 0;
#pragma unroll 1
                for (int tap = 0; tap < KW; ++tap) {
                    const int row = arow + tap;
                    const int v   = row & 7;
                    const int rb  = bo + row * 512;
                    int P[4];                      // addr for s=k; +128/(s>>2)
#pragma unroll
                    for (int k = 0; k < 4; ++k)
                        P[k] = rb + (((k * 2 + lh) ^ v) << 4);
                    int R0;                        // next (tap|h) s=0 addr
                    if (tap < KW - 1) {
                        const int r2 = row + 1;
                        R0 = bo + r2 * 512 + ((lh ^ (r2 & 7)) << 4);
                    } else if (h == 0) {
                        R0 = BUF_BYTES + arow * 512 + ((lh ^ (arow & 7)) << 4);
                    } else R0 = P[0];              // dummy (cold-load next seg)
                    const int t1 = tap * 32 + hb + 4;
                    int t2; bool pn = false;
                    if (tap < KW - 1)  t2 = tap * 32 + hb + 20;
                    else if (h == 0)   t2 = 4;
                    else             { t2 = -12; pn = true; }
#pragma unroll
                    for (int s = 0; s < 16; ++s) {
                        const bf16x8 a_n = *(const bf16x8*)(lds +
                            ((s < 15) ? P[(s + 1) & 3] + (((s + 1) >> 2) << 7)
                                      : R0));
                        __builtin_amdgcn_s_setprio(1);
                        acc[0] = __builtin_amdgcn_mfma_f32_32x32x16_bf16(
                            a_cur, Br[s & 3][0], acc[0], 0, 0, 0);
                        acc[1] = __builtin_amdgcn_mfma_f32_32x32x16_bf16(
                            a_cur, Br[s & 3][1], acc[1], 0, 0, 0);
                        __builtin_amdgcn_s_setprio(0);
                        // flat ring refill (depth 4); tail loads next stream
                        const int tk = (s < 12) ? (t1 + s) : (t2 + s);
                        const __bf16* p =
                            (((s >= 12) && pn) ? bpn : bpc) + (size_t)tk * 4096;
                        Br[s & 3][0] = *(const bf16x8*)(p);
                        Br[s & 3][1] = *(const bf16x8*)(p + 512);
                        a_cur = a_n;
                    }
                }
                if (h == 0 && lastc) {
                    __syncthreads();               // all buf0 reads done
                    writePair(lds, 0);
                    issuePair(nbs, 0, 2);          // short stall (serial)
                    writePair(lds, 2);
                    issuePair(nbs, 1, 0);          // hide under h1
                }
            }

            // ---- epilogue: masked max over t, cross-lane, cross-wave ----
            const int Tv = 126 - c;                // 126/125/124 valid
            float cmax[2];
#pragma unroll
            for (int nt = 0; nt < 2; ++nt) {
                float mx = -3.0e38f;
#pragma unroll
                for (int r = 0; r < 16; ++r) {
                    const int t = wm * 32 + (r & 3) + 8 * (r >> 2) + 4 * lh;
                    if (t < Tv) mx = fmaxf(mx, acc[nt][r]);
                }
                mx = fmaxf(mx, __shfl_xor(mx, 32, 64));
                cmax[nt] = mx;
            }
            __syncthreads();                       // buf1 reads done
            if (lastc) {
                writePair(lds + BUF_BYTES, 0);
                issuePair(nbs, 1, 2);              // short stall (serial)
                writePair(lds + BUF_BYTES, 2);
            }
            if (lane < 32) {
                red[wm * 256 + wn * 64 + l31]      = cmax[0];
                red[wm * 256 + wn * 64 + 32 + l31] = cmax[1];
            }
            __syncthreads();                       // red + buf1 writes done
            if (tid < 256) {
                const float* bias = (c == 0) ? b3 : (c == 1) ? b4 : b5;
                const float vv = fmaxf(fmaxf(red[tid], red[256 + tid]),
                                       fmaxf(red[512 + tid], red[768 + tid]))
                                 + bias[tid];
                out[(size_t)bs * 768 + c * 256 + tid] = fmaxf(vv, 0.f);
            }
        }
    }
}

extern "C" void kernel_launch(void* const* d_in, const int* in_sizes, int n_in,
                              void* d_out, int out_size, void* d_ws, size_t ws_size,
                              hipStream_t stream) {
    const int*   text  = (const int*)d_in[0];
    const float* embed = (const float*)d_in[1];
    const float* w3    = (const float*)d_in[2];
    const float* b3    = (const float*)d_in[3];
    const float* w4    = (const float*)d_in[4];
    const float* b4    = (const float*)d_in[5];
    const float* w5    = (const float*)d_in[6];
    const float* b5    = (const float*)d_in[7];
    float* out = (float*)d_out;

    __bf16* wq = (__bf16*)d_ws;                 // 1572864 bf16 = 3.1 MB

    (void)hipFuncSetAttribute((const void*)conv_gemm_kernel,
                              hipFuncAttributeMaxDynamicSharedMemorySize,
                              LDS_TOTAL);

    pack_w_kernel<<<768, 256, 0, stream>>>(w3, w4, w5, wq);
    conv_gemm_kernel<<<256, 1024, LDS_TOTAL, stream>>>(text, embed, wq,
                                                       b3, b4, b5, out);
}

// Round 5
// 496.522 us; speedup vs baseline: 1.0753x; 1.0753x over previous
//
#include <hip/hip_runtime.h>
#include <hip/hip_bf16.h>

// Problem: B=16,S=64 -> BS=1024 sequences, L=128 tokens, D=512, F=256 filters
// per conv width Kw in {3,4,5}, V=30000.
// out[bs, c*256 + f] = relu(max_t (conv_c(x)[t,f]) + b_c[f]), fp32.
//
// R7: persistent c-merged blocks, 16x16x32 (2m x 8n), depth-4 B ring: 442 us
//     (conv 363, Mfma 58%).
// R8: 32x32x16 at (4m x 4n) FAILED (conv 490, Mfma 39%): B per k16-step
//     doubled to 32 KB/CU while the gather thrashed wq out of L2 -> B fell
//     to L3 at ~600 cyc -> 766 cyc/step vs 258 ideal. Bank conflicts are
//     the inherent b128 cost (~124 B/cyc LDS effective), layout-invariant.
// R9: 32x32x16 at (2m x 8n) = R7's traffic shape (A 32 KB, B 16 KB per k16)
//     with the 2495 TF rate (floor 165 us) and half the MFMA instrs.
//     (a) NON-TEMPORAL embed gather -> wq stays L2-resident -> B = L2 hits.
//     (b) tap-outer/d-linear B stream: chunk idx == step idx; depth-4 ring
//     never drains across dh/tap/conv/bs (tail slots prefetch next stream).
//     (c) restage at conv-2 end only (both slabs read until then); first
//     gather pair issued at c2 start (T14, hidden under 160-step K loop).
// R9b: compile fix — nontemporal builtin needs clang vector type, not
//     HIP_vector_type float4; use ext_vector_type(4) alias.

typedef __bf16 bf16x8 __attribute__((ext_vector_type(8)));
typedef float f32x16 __attribute__((ext_vector_type(16)));
typedef float f32x4v __attribute__((ext_vector_type(4)));

#define ROWS 132                      // 128 real + 4 zero rows (K=5 window)
#define ROWB 512                      // bytes per row per half-D buffer
#define BUF_BYTES (ROWS * ROWB)       // 67584
#define RED_OFF (2 * BUF_BYTES)       // 135168
#define LDS_TOTAL (RED_OFF + 2048)    // 137216 (red: 2 x 256 f32)

// -------- pack_w: 32x32-fragment-ordered chunks (unchanged from R8) ---------
// Chunk g = (c, k16, n32), 1024 B = 64 lanes x 16 B. Element (lane, j):
//   f = n32*32 + (lane&31), tap = k16>>5, d = (k16&31)*16 + (lane>>5)*8 + j
//   src = w_c[f][d][tap]  (layout [F][D][Kw]).  Chunk order: [c][k16][n32].
__global__ void pack_w_kernel(const float* __restrict__ w3,
                              const float* __restrict__ w4,
                              const float* __restrict__ w5,
                              __bf16* __restrict__ wq) {
    const int t    = blockIdx.x * 256 + threadIdx.x;  // 0..196607
    const int g    = t >> 6;                          // chunk 0..3071
    const int lane = t & 63;
    int rel, Kw; const float* w;
    if (g < 768)       { rel = g;        Kw = 3; w = w3; }
    else if (g < 1792) { rel = g - 768;  Kw = 4; w = w4; }
    else               { rel = g - 1792; Kw = 5; w = w5; }
    const int k16 = rel >> 3;                         // 0..Kw*32-1
    const int n32 = rel & 7;
    const int f   = n32 * 32 + (lane & 31);
    const int tap = k16 >> 5;
    const int d0  = (k16 & 31) * 16 + (lane >> 5) * 8;
    const float* src = w + ((size_t)f * 512 + d0) * Kw + tap;
    bf16x8 o;
#pragma unroll
    for (int j = 0; j < 8; ++j) o[j] = (__bf16)src[j * Kw];
    *(bf16x8*)(wq + (size_t)t * 8) = o;
}

// ---------------- persistent fused gather + conv GEMM -----------------------
// Grid 256 (1 block/CU), 4 bs/block, 1024 thr = 16 waves as 2m x 8n.
// Wave tile 64x32 = 2x1 of 32x32x16 bf16 (acc 2 x f32x16). A: two half-D
// slabs, XOR-swizzled, resident across all 3 convs. B: one 1 KB chunk per
// step per wave, flat depth-4 register ring, linear chunk index.
__global__ __launch_bounds__(1024, 4) void conv_gemm_kernel(
        const int* __restrict__ text,
        const float* __restrict__ embed,
        const __bf16* __restrict__ wq,
        const float* __restrict__ b3,
        const float* __restrict__ b4,
        const float* __restrict__ b5,
        float* __restrict__ out) {
    extern __shared__ char lds[];
    float* const red = (float*)(lds + RED_OFF);

    const int tid  = threadIdx.x;
    const int lane = tid & 63;
    const int wave = tid >> 6;         // 0..15
    const int wm   = wave & 1;         // m-slice (64 rows)
    const int wn   = wave >> 1;        // n-slice (32 cols)
    const int l31  = lane & 31;
    const int lh   = lane >> 5;
    const int sr   = tid >> 5;         // staging row-in-pass 0..31
    const int sc   = tid & 31;         // staging col 0..31 (x16B)

    const int bsbase = blockIdx.x * 4;

    // A fragment row base + swizzled step-0 address (constant per block)
    const int arow = wm * 64 + l31;
    const int av   = arow & 7;
    const int A00  = arow * 512 + ((av >> 1) << 5) + ((lh ^ (av & 1)) << 4);

    const __bf16* const bpL = wq + (size_t)wn * 512 + (size_t)lane * 8;

    // ---- gather staging: nt loads, 2 rows/thread-pass, 16 B dst/thread ----
    f32x4v G[4];
    auto issuePair = [&](int nbs, int h, int p0) {
#pragma unroll
        for (int p = 0; p < 2; ++p) {
            const int r = (p0 + p) * 32 + sr;
            const int tok = text[nbs * 128 + r];
            const f32x4v* src = (const f32x4v*)
                (embed + (size_t)tok * 512 + h * 256 + sc * 8);
            G[p * 2]     = __builtin_nontemporal_load(src);
            G[p * 2 + 1] = __builtin_nontemporal_load(src + 1);
        }
    };
    auto writePair = [&](char* bufp, int p0) {
#pragma unroll
        for (int p = 0; p < 2; ++p) {
            const int r = (p0 + p) * 32 + sr;
            const f32x4v v0 = G[p * 2], v1 = G[p * 2 + 1];
            bf16x8 o;
            o[0] = (__bf16)v0.x; o[1] = (__bf16)v0.y;
            o[2] = (__bf16)v0.z; o[3] = (__bf16)v0.w;
            o[4] = (__bf16)v1.x; o[5] = (__bf16)v1.y;
            o[6] = (__bf16)v1.z; o[7] = (__bf16)v1.w;
            *(bf16x8*)(bufp + r * ROWB + ((sc ^ (r & 7)) << 4)) = o;
        }
    };

    f32x16 acc[2];
    bf16x8 Br[4];
    bf16x8 a0, a1;

    // ---- block prolog: stage bs0 both halves, zero pad rows, fill ring ----
    issuePair(bsbase, 0, 0); writePair(lds, 0);
    issuePair(bsbase, 0, 2); writePair(lds, 2);
    issuePair(bsbase, 1, 0); writePair(lds + BUF_BYTES, 0);
    issuePair(bsbase, 1, 2); writePair(lds + BUF_BYTES, 2);
    if (tid < 128) {                   // rows 128..131, both buffers, once
        const int r = 128 + sr;
        const int off = r * ROWB + ((sc ^ (r & 7)) << 4);
        bf16x8 z = {};
        *(bf16x8*)(lds + off) = z;
        *(bf16x8*)(lds + BUF_BYTES + off) = z;
    }
#pragma unroll
    for (int k = 0; k < 4; ++k)        // ring: c0 chunks (k16) 0..3
        Br[k] = *(const bf16x8*)(bpL + (size_t)k * 4096);
    __syncthreads();

#pragma unroll 1
    for (int i = 0; i < 4; ++i) {
        const int bs  = bsbase + i;
        const int nbs = bs + 1;
        const bool stg = (i < 3);
#pragma unroll 1
        for (int c = 0; c < 3; ++c) {
            const int KW = 3 + c;
            const size_t cb  = (c == 0) ? 0 : (c == 1) ? 393216 : 917504;
            const size_t cbn = (c == 0) ? 393216 : (c == 1) ? 917504 : 0;
            const __bf16* bpc = bpL + cb;
            const __bf16* bpn = bpL + cbn;
            const bool lastc = stg && (c == 2);

#pragma unroll
            for (int r = 0; r < 16; ++r) { acc[0][r] = 0.f; acc[1][r] = 0.f; }

            if (lastc) issuePair(nbs, 0, 0);   // hide gather under c2 K loop

            // cold A for step 0 (slab may have been restaged)
            a0 = *(const bf16x8*)(lds + A00);
            a1 = *(const bf16x8*)(lds + A00 + 16384);

#pragma unroll 1
            for (int tap = 0; tap < KW; ++tap) {
                const int row = arow + tap;
                const int v = row & 7, u = v >> 1;
                const int Base = row * 512 + ((lh ^ (v & 1)) << 4);
                int P[4];
#pragma unroll
                for (int r = 0; r < 4; ++r) P[r] = Base + ((r ^ u) << 5);
                const int r2 = row + 1, v2 = r2 & 7;   // next-tap d0 (buf0)
                const int NT0 = r2 * 512 + ((v2 >> 1) << 5)
                                         + ((lh ^ (v2 & 1)) << 4);
#pragma unroll
                for (int dh = 0; dh < 2; ++dh) {
                    const int bo = dh ? BUF_BYTES : 0;
                    const int s0 = tap * 32 + dh * 16;
                    // B refill bases: chunk index s0+4+d (d<12), else next
                    // segment / next stream (tail) chunks 0..3.
                    const __bf16* q0 = bpc + (size_t)(s0 + 4) * 4096;
                    const __bf16* q1 = (dh == 1 && tap == KW - 1)
                                           ? bpn : (q0 + 12 * 4096);
#pragma unroll
                    for (int d = 0; d < 16; ++d) {
                        int na;
                        if (d < 15)
                            na = bo + P[(d + 1) & 3] + (((d + 1) >> 2) << 7);
                        else if (dh == 0)
                            na = BUF_BYTES + P[0];     // same tap, half 1
                        else
                            na = NT0;                  // next tap (or dummy)
                        const bf16x8 n0 = *(const bf16x8*)(lds + na);
                        const bf16x8 n1 = *(const bf16x8*)(lds + na + 16384);
                        __builtin_amdgcn_s_setprio(1);
                        acc[0] = __builtin_amdgcn_mfma_f32_32x32x16_bf16(
                            a0, Br[d & 3], acc[0], 0, 0, 0);
                        acc[1] = __builtin_amdgcn_mfma_f32_32x32x16_bf16(
                            a1, Br[d & 3], acc[1], 0, 0, 0);
                        __builtin_amdgcn_s_setprio(0);
                        Br[d & 3] = (d < 12)
                            ? *(const bf16x8*)(q0 + (size_t)d * 4096)
                            : *(const bf16x8*)(q1 + (size_t)(d - 12) * 4096);
                        a0 = n0; a1 = n1;
                    }
                }
            }

            // ---- epilogue: masked max over t, cross-lane, cross-wave ----
            const int Tv = 126 - c;                // 126/125/124 valid
            float cmax = -3.0e38f;
#pragma unroll
            for (int mt = 0; mt < 2; ++mt)
#pragma unroll
                for (int r = 0; r < 16; ++r) {
                    const int t = wm * 64 + mt * 32
                                + (r & 3) + 8 * (r >> 2) + 4 * lh;
                    if (t < Tv) cmax = fmaxf(cmax, acc[mt][r]);
                }
            cmax = fmaxf(cmax, __shfl_xor(cmax, 32, 64));

            __syncthreads();   // all slab reads + prev red consumers done
            if (lane < 32) red[wm * 256 + wn * 32 + l31] = cmax;
            if (lastc) {       // restage bs+1 (p0 already in flight)
                writePair(lds, 0);
                issuePair(nbs, 0, 2); writePair(lds, 2);
                issuePair(nbs, 1, 0); writePair(lds + BUF_BYTES, 0);
                issuePair(nbs, 1, 2); writePair(lds + BUF_BYTES, 2);
            }
            __syncthreads();   // red + restage writes visible
            if (tid < 256) {
                const float* bias = (c == 0) ? b3 : (c == 1) ? b4 : b5;
                const float vv = fmaxf(red[tid], red[256 + tid]) + bias[tid];
                __builtin_nontemporal_store(fmaxf(vv, 0.f),
                    &out[(size_t)bs * 768 + c * 256 + tid]);
            }
        }
    }
}

extern "C" void kernel_launch(void* const* d_in, const int* in_sizes, int n_in,
                              void* d_out, int out_size, void* d_ws, size_t ws_size,
                              hipStream_t stream) {
    const int*   text  = (const int*)d_in[0];
    const float* embed = (const float*)d_in[1];
    const float* w3    = (const float*)d_in[2];
    const float* b3    = (const float*)d_in[3];
    const float* w4    = (const float*)d_in[4];
    const float* b4    = (const float*)d_in[5];
    const float* w5    = (const float*)d_in[6];
    const float* b5    = (const float*)d_in[7];
    float* out = (float*)d_out;

    __bf16* wq = (__bf16*)d_ws;                 // 1572864 bf16 = 3.1 MB

    (void)hipFuncSetAttribute((const void*)conv_gemm_kernel,
                              hipFuncAttributeMaxDynamicSharedMemorySize,
                              LDS_TOTAL);

    pack_w_kernel<<<768, 256, 0, stream>>>(w3, w4, w5, wq);
    conv_gemm_kernel<<<256, 1024, LDS_TOTAL, stream>>>(text, embed, wq,
                                                       b3, b4, b5, out);
}